// Round 2
// baseline (208.007 us; speedup 1.0000x reference)
//
#include <hip/hip_runtime.h>

#define HH 128
#define WW 128
#define CC 96
#define KK 7

// 12-col window row held as 3 float4s (value semantics -> reliable SROA).
struct Row { float4 a, b, c; };

__device__ __forceinline__ float elem(const Row& r, int k) {
  // k is a compile-time constant after full unroll; switch folds away.
  switch (k) {
    case 0:  return r.a.x; case 1:  return r.a.y; case 2:  return r.a.z; case 3:  return r.a.w;
    case 4:  return r.b.x; case 5:  return r.b.y; case 6:  return r.b.z; case 7:  return r.b.w;
    case 8:  return r.c.x; case 9:  return r.c.y; case 10: return r.c.z; default: return r.c.w;
  }
}

__device__ __forceinline__ Row load_row(const float* __restrict__ xp, int r,
                                        int tc0, bool lok, bool rok) {
  Row o;
  const float4 z = make_float4(0.f, 0.f, 0.f, 0.f);
  if ((unsigned)r < (unsigned)HH) {
    const float* p = xp + r * WW + tc0 - 4;
    o.a = lok ? *(const float4*)(p)     : z;   // branch keeps OOB lanes from loading
    o.b =       *(const float4*)(p + 4);
    o.c = rok ? *(const float4*)(p + 8) : z;
  } else {
    o.a = z; o.b = z; o.c = z;
  }
  return o;
}

// One kernel-row contribution for output col q: 7 adds + max3-friendly tree.
__device__ __forceinline__ float tapq(const Row& r, int q, const float* wr, float m) {
  float t0 = elem(r, q + 1) + wr[0];
  float t1 = elem(r, q + 2) + wr[1];
  float t2 = elem(r, q + 3) + wr[2];
  float t3 = elem(r, q + 4) + wr[3];
  float t4 = elem(r, q + 5) + wr[4];
  float t5 = elem(r, q + 6) + wr[5];
  float t6 = elem(r, q + 7) + wr[6];
  float u0 = fmaxf(fmaxf(t0, t1), t2);      // v_max3
  float u1 = fmaxf(fmaxf(t3, t4), t5);      // v_max3
  return fmaxf(fmaxf(m, t6), fmaxf(u0, u1)); // v_max3 + v_max
}

#define TAP_ROW(R, I)                              \
  m0 = tapq(R, 0, wv + (I)*7, m0);                 \
  m1 = tapq(R, 1, wv + (I)*7, m1);                 \
  m2 = tapq(R, 2, wv + (I)*7, m2);                 \
  m3 = tapq(R, 3, wv + (I)*7, m3);

__global__ __launch_bounds__(256) void morph_kernel(
    const float* __restrict__ x, const float* __restrict__ weight,
    float* __restrict__ out) {
  const int t = threadIdx.x;
  const int cg = t & 31;   // col group 0..31 -> out cols [4*cg, 4*cg+4)
  const int rg = t >> 5;   // row group 0..7  -> out rows [base + 8*rg, +8)
  const int half = blockIdx.x & 1;
  const int plane = blockIdx.x >> 1;  // b*CC + c
  const int c = plane % CC;

  const float* __restrict__ xp = x + (size_t)plane * (HH * WW);
  float* __restrict__ op = out + (size_t)plane * (HH * WW);
  const float* __restrict__ Wc = weight + c * (KK * KK);

  // 49 channel weights, block-uniform -> force scalar regs.
  float wv[KK * KK];
#pragma unroll
  for (int k = 0; k < KK * KK; ++k)
    wv[k] = __int_as_float(__builtin_amdgcn_readfirstlane(__float_as_int(Wc[k])));

  const int tc0 = cg << 2;
  const int row0 = half * 64 + rg * 8;
  const bool lok = (tc0 >= 4);
  const bool rok = (tc0 <= WW - 8);

  // Sliding 7-row window in named value structs: rotation = SSA rename.
  Row r0 = load_row(xp, row0 - 3, tc0, lok, rok);
  Row r1 = load_row(xp, row0 - 2, tc0, lok, rok);
  Row r2 = load_row(xp, row0 - 1, tc0, lok, rok);
  Row r3 = load_row(xp, row0 + 0, tc0, lok, rok);
  Row r4 = load_row(xp, row0 + 1, tc0, lok, rok);
  Row r5 = load_row(xp, row0 + 2, tc0, lok, rok);

#pragma unroll
  for (int orow = 0; orow < 8; ++orow) {
    Row r6 = load_row(xp, row0 + 3 + orow, tc0, lok, rok);

    // ReLU folded: accumulators start at 0 == max(0, .)
    float m0 = 0.f, m1 = 0.f, m2 = 0.f, m3 = 0.f;
    TAP_ROW(r0, 0)
    TAP_ROW(r1, 1)
    TAP_ROW(r2, 2)
    TAP_ROW(r3, 3)
    TAP_ROW(r4, 4)
    TAP_ROW(r5, 5)
    TAP_ROW(r6, 6)

    *(float4*)(op + (size_t)(row0 + orow) * WW + tc0) = make_float4(m0, m1, m2, m3);

    r0 = r1; r1 = r2; r2 = r3; r3 = r4; r4 = r5; r5 = r6;
  }
}

extern "C" void kernel_launch(void* const* d_in, const int* in_sizes, int n_in,
                              void* d_out, int out_size, void* d_ws, size_t ws_size,
                              hipStream_t stream) {
  const float* x = (const float*)d_in[0];
  const float* w = (const float*)d_in[1];
  float* out = (float*)d_out;
  const int nblocks = 16 * CC * 2;  // 16 batches * 96 channels * 2 half-planes
  morph_kernel<<<nblocks, 256, 0, stream>>>(x, w, out);
}